// Round 10
// baseline (146.298 us; speedup 1.0000x reference)
//
#include <hip/hip_runtime.h>
#include <hip/hip_bf16.h>

#define Bn 8
#define Cn 256
#define Hn 128
#define Wn 128
#define HWn (Hn * Wn)

typedef __attribute__((ext_vector_type(8))) short bfrag8;       // MFMA A/B frag (8 bf16)
typedef __attribute__((ext_vector_type(8))) unsigned short u16x8;
typedef __attribute__((ext_vector_type(4))) float f32x4;
typedef __attribute__((ext_vector_type(4))) unsigned int u32x4;

__device__ __forceinline__ float bf2f(unsigned short u) {
    unsigned int v = ((unsigned int)u) << 16;
    return __builtin_bit_cast(float, v);
}
__device__ __forceinline__ unsigned short f2bf(float f) {
    unsigned int u = __builtin_bit_cast(unsigned int, f);
    unsigned int lsb = (u >> 16) & 1u;
    u += 0x7fffu + lsb;   // round-to-nearest-even (finite inputs)
    return (unsigned short)(u >> 16);
}

// ---------------------------------------------------------------------------
// Kernel 0: w_comb2[o][c] = (sum_k w_W[o,k] * w_pc[k,c]) * w_dw[c], stored
// PRE-SWIZZLED in MFMA fragment order:
//   frag[ob][ks][lane][e] = w_comb2[ob*16 + (lane&15)][ks*32 + (lane>>4)*8 + e]
// so the main kernel's A-fragment load is 64 lanes x 16 B fully contiguous.
// ---------------------------------------------------------------------------
__global__ __launch_bounds__(256)
void build_wcomb(const float* __restrict__ w_dw,
                 const float* __restrict__ w_pc,
                 const float* __restrict__ w_W,
                 unsigned short* __restrict__ wfrag) {
    const int o = blockIdx.x;
    const int c = threadIdx.x;
    float acc = 0.f;
#pragma unroll 8
    for (int k = 0; k < Cn; ++k)
        acc = fmaf(w_W[o * Cn + k], w_pc[k * Cn + c], acc);
    const int ob = o >> 4, lr = o & 15;
    const int ks = c >> 5, lg = (c & 31) >> 3, e = c & 7;
    const int lane = (lg << 4) + lr;
    wfrag[((((ob << 3) + ks) << 6) + lane) * 8 + e] = f2bf(acc * w_dw[c]);
}

// ---------------------------------------------------------------------------
// Kernel 1: per 64-pixel tile: transpose x -> x_t[B,H,W,C] (bf16) and compute
// sample coords (ix, iy) from tanh(w_off . x + b_off).
// ---------------------------------------------------------------------------
__global__ __launch_bounds__(256)
void prep_kernel(const float* __restrict__ x,
                 const float* __restrict__ w_off,
                 const float* __restrict__ b_off,
                 unsigned short* __restrict__ x_t,    // [B*HW][C] bf16
                 float2* __restrict__ coords) {       // [B*HW] (ix, iy)
    __shared__ __align__(16) char tile[64 * 512];     // 64 pix x 256 bf16, XOR-swizzled
    __shared__ float partial[4][64][2];
    const int t = threadIdx.x;
    const int lane = t & 63;
    const int wv = t >> 6;                 // 0..3 (wave id)
    int blk = blockIdx.x;                  // 2048 blocks
    blk = ((blk & 7) << 8) | (blk >> 3);   // XCD swizzle: image b = XCD id
    const int b = blk >> 8;
    const int p0 = (blk & 255) << 6;
    const float* xp = x + ((size_t)b * Cn) * HWn + p0;

    float s0 = 0.f, s1 = 0.f;
#pragma unroll 8
    for (int i = 0; i < 64; ++i) {
        int c = (wv << 6) + i;
        float v = xp[(size_t)c * HWn + lane];
        s0 = fmaf(v, w_off[c], s0);
        s1 = fmaf(v, w_off[Cn + c], s1);
        int byte = (lane << 9) + (((c << 1)) ^ ((lane & 7) << 4));
        *reinterpret_cast<unsigned short*>(tile + byte) = f2bf(v);
    }
    partial[wv][lane][0] = s0;
    partial[wv][lane][1] = s1;
    __syncthreads();

    if (t < 64) {
        float o0 = partial[0][t][0] + partial[1][t][0] + partial[2][t][0] + partial[3][t][0] + b_off[0];
        float o1 = partial[0][t][1] + partial[1][t][1] + partial[2][t][1] + partial[3][t][1] + b_off[1];
        o0 = tanhf(o0);
        o1 = tanhf(o1);
        int p = p0 + t;
        int yy = p >> 7, xx = p & 127;
        float gx = fminf(fmaxf(-1.f + xx * (2.f / 127.f) + o0, -1.f), 1.f);
        float gy = fminf(fmaxf(-1.f + yy * (2.f / 127.f) + o1, -1.f), 1.f);
        // ix = ((gx+1)*W - 1)/2 = 64*gx + 63.5 ; same for iy (H=W=128)
        coords[(size_t)b * HWn + p] = make_float2(gx * 64.f + 63.5f, gy * 64.f + 63.5f);
    }

    // write-out: 4 threads per pixel, 64 channels each (contiguous bf16 rows)
    const int pp = t >> 2, cc = t & 3;
    unsigned short* dst = x_t + ((size_t)(b * HWn + p0 + pp)) * Cn + (cc << 6);
#pragma unroll
    for (int j = 0; j < 8; ++j) {
        int c2 = ((cc << 6) + (j << 3)) << 1;
        int byte = (pp << 9) + (c2 ^ ((pp & 7) << 4));
        *reinterpret_cast<u32x4*>(dst + (j << 3)) = *reinterpret_cast<const u32x4*>(tile + byte);
    }
}

// ---------------------------------------------------------------------------
// Kernel 2: per 64-pixel tile: gather+blend into swizzled LDS (each wave owns
// 16 px; lanes split 2 px/instruction -> 512 B contiguous per px row; two
// batches of 4 pixel-pairs). MFMA with coalesced fragment loads from wfrag.
// Streaming flows (x residual read, out write) are NON-TEMPORAL so L2/L3
// stay reserved for the reused gather data (x_t).
//   out[o][p] = sum_c w_comb2[o][c]*samp[p][c] + b_W[o] + x[b][o][p]
// ---------------------------------------------------------------------------
__global__ __launch_bounds__(256, 4)
void main_kernel(const float* __restrict__ x,
                 const float* __restrict__ b_W,
                 const unsigned short* __restrict__ x_t,
                 const float2* __restrict__ coords,
                 const unsigned short* __restrict__ wfrag,
                 float* __restrict__ out) {
    __shared__ __align__(16) char As[64 * 512];   // 64 pix x 256 bf16 sampled tile
    const int t = threadIdx.x;
    const int lane = t & 63;
    const int wid = t >> 6;          // 0..3
    int blk = blockIdx.x;            // 2048 blocks
    blk = ((blk & 7) << 8) | (blk >> 3);   // XCD swizzle: image b = XCD id
    const int b = blk >> 8;
    const int p0 = (blk & 255) << 6;
    const size_t pixbase = (size_t)b * HWn + p0;
    const unsigned short* xtb = x_t + (size_t)b * HWn * Cn;

    // ---- gather phase ----
    {
        const int half = lane >> 5;        // which pixel of the pair
        const int ch0 = (lane & 31) << 3;  // this lane's 8-channel chunk
        const int pw = (wid << 4) + half;  // wave's pixel base + my parity

        // preload coords for my 8 pixels (independent, all in flight)
        float2 co[8];
#pragma unroll
        for (int i = 0; i < 8; ++i)
            co[i] = coords[pixbase + pw + (i << 1)];

#pragma unroll
        for (int g = 0; g < 2; ++g) {
            u16x8 C00[4], C01[4], C10[4], C11[4];
            float W00[4], W01[4], W10[4], W11[4];

            // issue this batch's 16 corner loads before any blend
#pragma unroll
            for (int i = 0; i < 4; ++i) {
                const int ii = (g << 2) + i;
                float ix = co[ii].x, iy = co[ii].y;
                float fx = floorf(ix), fy = floorf(iy);
                int ix0 = (int)fx, iy0 = (int)fy;
                float wx1 = ix - fx, wy1 = iy - fy;
                float wx0 = 1.f - wx1, wy0 = 1.f - wy1;
                float w00 = wy0 * wx0, w01 = wy0 * wx1, w10 = wy1 * wx0, w11 = wy1 * wx1;
                bool vx0 = (ix0 >= 0) && (ix0 < Wn);
                bool vx1 = (ix0 >= -1) && (ix0 < Wn - 1);
                bool vy0 = (iy0 >= 0) && (iy0 < Hn);
                bool vy1 = (iy0 >= -1) && (iy0 < Hn - 1);
                if (!(vy0 && vx0)) w00 = 0.f;
                if (!(vy0 && vx1)) w01 = 0.f;
                if (!(vy1 && vx0)) w10 = 0.f;
                if (!(vy1 && vx1)) w11 = 0.f;
                W00[i] = w00; W01[i] = w01; W10[i] = w10; W11[i] = w11;
                int cx0 = min(max(ix0, 0), Wn - 1), cx1 = min(max(ix0 + 1, 0), Wn - 1);
                int cy0 = min(max(iy0, 0), Hn - 1), cy1 = min(max(iy0 + 1, 0), Hn - 1);
                const unsigned short* r0 = xtb + (size_t)(cy0 * Wn) * Cn + ch0;
                const unsigned short* r1 = xtb + (size_t)(cy1 * Wn) * Cn + ch0;
                C00[i] = *reinterpret_cast<const u16x8*>(r0 + (size_t)cx0 * Cn);
                C01[i] = *reinterpret_cast<const u16x8*>(r0 + (size_t)cx1 * Cn);
                C10[i] = *reinterpret_cast<const u16x8*>(r1 + (size_t)cx0 * Cn);
                C11[i] = *reinterpret_cast<const u16x8*>(r1 + (size_t)cx1 * Cn);
            }

#pragma unroll
            for (int i = 0; i < 4; ++i) {
                float w00 = W00[i], w01 = W01[i], w10 = W10[i], w11 = W11[i];
                u16x8 a = C00[i], bq = C01[i], c = C10[i], d = C11[i];
                u16x8 res;
#pragma unroll
                for (int e = 0; e < 8; ++e) {
                    float r = w00 * bf2f(a[e]) + w01 * bf2f(bq[e])
                            + w10 * bf2f(c[e]) + w11 * bf2f(d[e]);
                    res[e] = f2bf(r);
                }
                int pl = pw + (((g << 2) + i) << 1);
                int byte = (pl << 9) + ((ch0 << 1) ^ ((pl & 7) << 4));
                *reinterpret_cast<u16x8*>(As + byte) = res;
            }
        }
    }
    __syncthreads();

    // ---- MFMA phase: 4 waves; wave wid owns o-range [wid*64, wid*64+64), all 64 px
    const int obase = wid << 6;
    const int lr = lane & 15;
    const int lg = lane >> 4;
    f32x4 acc[4][4];
#pragma unroll
    for (int m = 0; m < 4; ++m)
#pragma unroll
        for (int n = 0; n < 4; ++n)
            acc[m][n] = (f32x4){0.f, 0.f, 0.f, 0.f};

#pragma unroll
    for (int ks = 0; ks < 8; ++ks) {
        int k0 = (ks << 5) + (lg << 3);
        bfrag8 a[4], bb[4];
#pragma unroll
        for (int m = 0; m < 4; ++m) {
            // coalesced fragment load: 64 lanes x 16 B contiguous (1 KB)
            const unsigned short* src = wfrag + (((((wid << 2) + m) << 3) + ks) << 9) + (lane << 3);
            a[m] = *reinterpret_cast<const bfrag8*>(src);
        }
#pragma unroll
        for (int n = 0; n < 4; ++n) {
            int pr = (n << 4) + lr;
            int byte = (pr << 9) + ((k0 << 1) ^ ((pr & 7) << 4));
            bb[n] = *reinterpret_cast<const bfrag8*>(As + byte);
        }
#pragma unroll
        for (int m = 0; m < 4; ++m)
#pragma unroll
            for (int n = 0; n < 4; ++n)
                acc[m][n] = __builtin_amdgcn_mfma_f32_16x16x32_bf16(a[m], bb[n], acc[m][n], 0, 0, 0);
    }

    // ---- epilogue: D col = lane&15 (pixel), row = lg*4+reg (o)
    // nt-load x (streaming, never reused) + nt-store out (never re-read):
    // keep L2/L3 capacity for x_t gather rows.
#pragma unroll
    for (int m = 0; m < 4; ++m) {
#pragma unroll
        for (int r = 0; r < 4; ++r) {
            int o = obase + (m << 4) + (lg << 2) + r;
            float bw = b_W[o];
            size_t rowbase = ((size_t)b * Cn + o) * HWn + p0;
#pragma unroll
            for (int n = 0; n < 4; ++n) {
                size_t idx = rowbase + (n << 4) + lr;
                float xv = __builtin_nontemporal_load(&x[idx]);
                __builtin_nontemporal_store(acc[m][n][r] + bw + xv, &out[idx]);
            }
        }
    }
}

extern "C" void kernel_launch(void* const* d_in, const int* in_sizes, int n_in,
                              void* d_out, int out_size, void* d_ws, size_t ws_size,
                              hipStream_t stream) {
    const float* x     = (const float*)d_in[0];
    const float* w_dw  = (const float*)d_in[1];
    const float* w_off = (const float*)d_in[2];
    const float* b_off = (const float*)d_in[3];
    const float* w_pc  = (const float*)d_in[4];
    const float* w_W   = (const float*)d_in[5];
    const float* b_W   = (const float*)d_in[6];
    float* out = (float*)d_out;

    char* ws = (char*)d_ws;
    unsigned short* x_t   = (unsigned short*)ws;                        // 67,108,864 B
    float2* coords        = (float2*)(ws + 67108864);                   //  1,048,576 B
    unsigned short* wcomb = (unsigned short*)(ws + 67108864 + 1048576); //    131,072 B

    build_wcomb<<<dim3(256), dim3(256), 0, stream>>>(w_dw, w_pc, w_W, wcomb);
    prep_kernel<<<dim3(2048), dim3(256), 0, stream>>>(x, w_off, b_off, x_t, coords);
    main_kernel<<<dim3(2048), dim3(256), 0, stream>>>(x, b_W, x_t, coords, wcomb, out);
}

// Round 12
// 138.729 us; speedup vs baseline: 1.0546x; 1.0546x over previous
//
#include <hip/hip_runtime.h>
#include <hip/hip_bf16.h>

#define Bn 8
#define Cn 256
#define Hn 128
#define Wn 128
#define HWn (Hn * Wn)

typedef __attribute__((ext_vector_type(8))) short bfrag8;       // MFMA A/B frag (8 bf16)
typedef __attribute__((ext_vector_type(8))) unsigned short u16x8;
typedef __attribute__((ext_vector_type(4))) float f32x4;
typedef __attribute__((ext_vector_type(4))) unsigned int u32x4;

__device__ __forceinline__ float bf2f(unsigned short u) {
    unsigned int v = ((unsigned int)u) << 16;
    return __builtin_bit_cast(float, v);
}
__device__ __forceinline__ unsigned short f2bf(float f) {
    unsigned int u = __builtin_bit_cast(unsigned int, f);
    unsigned int lsb = (u >> 16) & 1u;
    u += 0x7fffu + lsb;   // round-to-nearest-even (finite inputs)
    return (unsigned short)(u >> 16);
}

// global->LDS DMA, 16 B per lane; dest = ldsbase + lane*16 (wave-uniform base)
__device__ __forceinline__ void load_lds16(const void* g, void* l) {
    __builtin_amdgcn_global_load_lds(
        (const __attribute__((address_space(1))) unsigned int*)g,
        (__attribute__((address_space(3))) unsigned int*)l,
        16, 0, 0);
}

// ---------------------------------------------------------------------------
// Kernel 0: w_comb2[o][c] = (sum_k w_W[o,k] * w_pc[k,c]) * w_dw[c], stored
// PRE-SWIZZLED in MFMA fragment order:
//   frag[ob][ks][lane][e] = w_comb2[ob*16 + (lane&15)][ks*32 + (lane>>4)*8 + e]
// ---------------------------------------------------------------------------
__global__ __launch_bounds__(256)
void build_wcomb(const float* __restrict__ w_dw,
                 const float* __restrict__ w_pc,
                 const float* __restrict__ w_W,
                 unsigned short* __restrict__ wfrag) {
    const int o = blockIdx.x;
    const int c = threadIdx.x;
    float acc = 0.f;
#pragma unroll 8
    for (int k = 0; k < Cn; ++k)
        acc = fmaf(w_W[o * Cn + k], w_pc[k * Cn + c], acc);
    const int ob = o >> 4, lr = o & 15;
    const int ks = c >> 5, lg = (c & 31) >> 3, e = c & 7;
    const int lane = (lg << 4) + lr;
    wfrag[((((ob << 3) + ks) << 6) + lane) * 8 + e] = f2bf(acc * w_dw[c]);
}

// ---------------------------------------------------------------------------
// Kernel 1: per 64-pixel tile: transpose x -> x_t[B,H,W,C] (bf16) and compute
// sample coords (ix, iy) from tanh(w_off . x + b_off).
// ---------------------------------------------------------------------------
__global__ __launch_bounds__(256)
void prep_kernel(const float* __restrict__ x,
                 const float* __restrict__ w_off,
                 const float* __restrict__ b_off,
                 unsigned short* __restrict__ x_t,    // [B*HW][C] bf16
                 float2* __restrict__ coords) {       // [B*HW] (ix, iy)
    __shared__ __align__(16) char tile[64 * 512];     // 64 pix x 256 bf16, XOR-swizzled
    __shared__ float partial[4][64][2];
    const int t = threadIdx.x;
    const int lane = t & 63;
    const int wv = t >> 6;                 // 0..3 (wave id)
    int blk = blockIdx.x;                  // 2048 blocks
    blk = ((blk & 7) << 8) | (blk >> 3);   // XCD swizzle: image b = XCD id
    const int b = blk >> 8;
    const int p0 = (blk & 255) << 6;
    const float* xp = x + ((size_t)b * Cn) * HWn + p0;

    float s0 = 0.f, s1 = 0.f;
#pragma unroll 8
    for (int i = 0; i < 64; ++i) {
        int c = (wv << 6) + i;
        float v = xp[(size_t)c * HWn + lane];
        s0 = fmaf(v, w_off[c], s0);
        s1 = fmaf(v, w_off[Cn + c], s1);
        int byte = (lane << 9) + (((c << 1)) ^ ((lane & 7) << 4));
        *reinterpret_cast<unsigned short*>(tile + byte) = f2bf(v);
    }
    partial[wv][lane][0] = s0;
    partial[wv][lane][1] = s1;
    __syncthreads();

    if (t < 64) {
        float o0 = partial[0][t][0] + partial[1][t][0] + partial[2][t][0] + partial[3][t][0] + b_off[0];
        float o1 = partial[0][t][1] + partial[1][t][1] + partial[2][t][1] + partial[3][t][1] + b_off[1];
        o0 = tanhf(o0);
        o1 = tanhf(o1);
        int p = p0 + t;
        int yy = p >> 7, xx = p & 127;
        float gx = fminf(fmaxf(-1.f + xx * (2.f / 127.f) + o0, -1.f), 1.f);
        float gy = fminf(fmaxf(-1.f + yy * (2.f / 127.f) + o1, -1.f), 1.f);
        // ix = ((gx+1)*W - 1)/2 = 64*gx + 63.5 ; same for iy (H=W=128)
        coords[(size_t)b * HWn + p] = make_float2(gx * 64.f + 63.5f, gy * 64.f + 63.5f);
    }

    // write-out: 4 threads per pixel, 64 channels each (contiguous bf16 rows)
    const int pp = t >> 2, cc = t & 3;
    unsigned short* dst = x_t + ((size_t)(b * HWn + p0 + pp)) * Cn + (cc << 6);
#pragma unroll
    for (int j = 0; j < 8; ++j) {
        int c2 = ((cc << 6) + (j << 3)) << 1;
        int byte = (pp << 9) + (c2 ^ ((pp & 7) << 4));
        *reinterpret_cast<u32x4*>(dst + (j << 3)) = *reinterpret_cast<const u32x4*>(tile + byte);
    }
}

// ---------------------------------------------------------------------------
// Kernel 2: per 32-pixel tile. Gather via global_load_lds DMA: 4 corner LDS
// buffers [32px][256ch] bf16 (linear dest, SOURCE-swizzled chunks
// chunk_lds = j, chunk_global = j ^ (px&15)); zero gather VGPRs -> all 16
// DMAs per wave in flight; one vmcnt(0)+barrier per tile. Blend happens at
// MFMA B-fragment read using per-pixel weights (validity pre-folded) in LDS.
//   out[o][p] = sum_c w_comb2[o][c]*samp[p][c] + b_W[o] + x[b][o][p]
// ---------------------------------------------------------------------------
__global__ __launch_bounds__(256, 4)
void main_kernel(const float* __restrict__ x,
                 const float* __restrict__ b_W,
                 const unsigned short* __restrict__ x_t,
                 const float2* __restrict__ coords,
                 const unsigned short* __restrict__ wfrag,
                 float* __restrict__ out) {
    __shared__ __align__(16) char As[4][32 * 512];   // 4 corners x 32px x 512B
    __shared__ __align__(16) float4 wts[32];         // per-pixel corner weights
    const int t = threadIdx.x;
    const int lane = t & 63;
    const int wid = t >> 6;          // 0..3
    int blk = blockIdx.x;            // 4096 blocks
    blk = ((blk & 7) << 9) | (blk >> 3);   // XCD swizzle: image b = XCD id
    const int b = blk >> 9;
    const int p0 = (blk & 511) << 5;       // 32-px tile
    const size_t pixbase = (size_t)b * HWn + p0;
    const unsigned short* xtb = x_t + (size_t)b * HWn * Cn;

    // ---- weights setup: one thread per pixel ----
    if (t < 32) {
        float2 co = coords[pixbase + t];
        float ix = co.x, iy = co.y;
        float fx = floorf(ix), fy = floorf(iy);
        int ix0 = (int)fx, iy0 = (int)fy;
        float wx1 = ix - fx, wy1 = iy - fy;
        float wx0 = 1.f - wx1, wy0 = 1.f - wy1;
        bool vx0 = (ix0 >= 0) && (ix0 < Wn);
        bool vx1 = (ix0 >= -1) && (ix0 < Wn - 1);
        bool vy0 = (iy0 >= 0) && (iy0 < Hn);
        bool vy1 = (iy0 >= -1) && (iy0 < Hn - 1);
        float4 w;
        w.x = (vy0 && vx0) ? wy0 * wx0 : 0.f;
        w.y = (vy0 && vx1) ? wy0 * wx1 : 0.f;
        w.z = (vy1 && vx0) ? wy1 * wx0 : 0.f;
        w.w = (vy1 && vx1) ? wy1 * wx1 : 0.f;
        wts[t] = w;
    }

    // ---- DMA gather: wave wid owns px [wid*8, wid*8+8) as 4 pixel-pairs ----
    {
        const int hp = lane >> 5;           // which pixel of the pair
        const int j = lane & 31;            // LDS chunk index (16B units)
        float2 co[4];
#pragma unroll
        for (int i = 0; i < 4; ++i)
            co[i] = coords[pixbase + (wid << 3) + (i << 1) + hp];

#pragma unroll
        for (int i = 0; i < 4; ++i) {
            const int p = (wid << 3) + (i << 1);   // pair base (wave-uniform)
            const int px = p + hp;                 // this lane's pixel
            float ix = co[i].x, iy = co[i].y;
            int ix0 = (int)floorf(ix), iy0 = (int)floorf(iy);
            int cx0 = min(max(ix0, 0), Wn - 1), cx1 = min(max(ix0 + 1, 0), Wn - 1);
            int cy0 = min(max(iy0, 0), Hn - 1), cy1 = min(max(iy0 + 1, 0), Hn - 1);
            const int gch = (j ^ (px & 15)) << 3;  // swizzled global channel base
            const unsigned short* s00 = xtb + (size_t)(cy0 * Wn + cx0) * Cn + gch;
            const unsigned short* s01 = xtb + (size_t)(cy0 * Wn + cx1) * Cn + gch;
            const unsigned short* s10 = xtb + (size_t)(cy1 * Wn + cx0) * Cn + gch;
            const unsigned short* s11 = xtb + (size_t)(cy1 * Wn + cx1) * Cn + gch;
            load_lds16(s00, &As[0][p << 9]);
            load_lds16(s01, &As[1][p << 9]);
            load_lds16(s10, &As[2][p << 9]);
            load_lds16(s11, &As[3][p << 9]);
        }
    }
    __syncthreads();   // drains DMA (vmcnt) + orders wts

    // ---- MFMA phase: 4 waves; wave wid owns o-range [wid*64, +64), all 32 px
    const int obase = wid << 6;
    const int lr = lane & 15;
    const int lg = lane >> 4;
    f32x4 acc[4][2];
#pragma unroll
    for (int m = 0; m < 4; ++m)
#pragma unroll
        for (int n = 0; n < 2; ++n)
            acc[m][n] = (f32x4){0.f, 0.f, 0.f, 0.f};

#pragma unroll
    for (int ks = 0; ks < 8; ++ks) {
        bfrag8 a[4], bb[2];
        const int kc = (ks << 2) + lg;           // 16B chunk index 0..31
#pragma unroll
        for (int n = 0; n < 2; ++n) {
            const int pr = (n << 4) + lr;
            const int off = (pr << 9) + ((kc ^ (pr & 15)) << 4);
            u16x8 c00 = *reinterpret_cast<const u16x8*>(&As[0][off]);
            u16x8 c01 = *reinterpret_cast<const u16x8*>(&As[1][off]);
            u16x8 c10 = *reinterpret_cast<const u16x8*>(&As[2][off]);
            u16x8 c11 = *reinterpret_cast<const u16x8*>(&As[3][off]);
            float4 w = wts[pr];
            u16x8 res;
#pragma unroll
            for (int e = 0; e < 8; ++e) {
                float r = w.x * bf2f(c00[e]) + w.y * bf2f(c01[e])
                        + w.z * bf2f(c10[e]) + w.w * bf2f(c11[e]);
                res[e] = f2bf(r);
            }
            bb[n] = __builtin_bit_cast(bfrag8, res);
        }
#pragma unroll
        for (int m = 0; m < 4; ++m) {
            // coalesced fragment load: 64 lanes x 16 B contiguous (1 KB)
            const unsigned short* src = wfrag + (((((wid << 2) + m) << 3) + ks) << 9) + (lane << 3);
            a[m] = *reinterpret_cast<const bfrag8*>(src);
        }
#pragma unroll
        for (int m = 0; m < 4; ++m)
#pragma unroll
            for (int n = 0; n < 2; ++n)
                acc[m][n] = __builtin_amdgcn_mfma_f32_16x16x32_bf16(a[m], bb[n], acc[m][n], 0, 0, 0);
    }

    // ---- epilogue: D col = lane&15 (pixel), row = lg*4+reg (o); nt out-store
#pragma unroll
    for (int m = 0; m < 4; ++m) {
#pragma unroll
        for (int r = 0; r < 4; ++r) {
            int o = obase + (m << 4) + (lg << 2) + r;
            float bw = b_W[o];
            size_t rowbase = ((size_t)b * Cn + o) * HWn + p0;
#pragma unroll
            for (int n = 0; n < 2; ++n) {
                size_t idx = rowbase + (n << 4) + lr;
                __builtin_nontemporal_store(acc[m][n][r] + bw + x[idx], &out[idx]);
            }
        }
    }
}

extern "C" void kernel_launch(void* const* d_in, const int* in_sizes, int n_in,
                              void* d_out, int out_size, void* d_ws, size_t ws_size,
                              hipStream_t stream) {
    const float* x     = (const float*)d_in[0];
    const float* w_dw  = (const float*)d_in[1];
    const float* w_off = (const float*)d_in[2];
    const float* b_off = (const float*)d_in[3];
    const float* w_pc  = (const float*)d_in[4];
    const float* w_W   = (const float*)d_in[5];
    const float* b_W   = (const float*)d_in[6];
    float* out = (float*)d_out;

    char* ws = (char*)d_ws;
    unsigned short* x_t   = (unsigned short*)ws;                        // 67,108,864 B
    float2* coords        = (float2*)(ws + 67108864);                   //  1,048,576 B
    unsigned short* wcomb = (unsigned short*)(ws + 67108864 + 1048576); //    131,072 B

    build_wcomb<<<dim3(256), dim3(256), 0, stream>>>(w_dw, w_pc, w_W, wcomb);
    prep_kernel<<<dim3(2048), dim3(256), 0, stream>>>(x, w_off, b_off, x_t, coords);
    main_kernel<<<dim3(4096), dim3(256), 0, stream>>>(x, b_W, x_t, coords, wcomb, out);
}

// Round 13
// 118.966 us; speedup vs baseline: 1.2297x; 1.1661x over previous
//
#include <hip/hip_runtime.h>
#include <hip/hip_bf16.h>

#define Bn 8
#define Cn 256
#define Hn 128
#define Wn 128
#define HWn (Hn * Wn)

typedef __attribute__((ext_vector_type(8))) short bfrag8;       // MFMA A/B frag (8 bf16)
typedef __attribute__((ext_vector_type(8))) unsigned short u16x8;
typedef __attribute__((ext_vector_type(4))) float f32x4;
typedef __attribute__((ext_vector_type(4))) unsigned int u32x4;

__device__ __forceinline__ float bf2f(unsigned short u) {
    unsigned int v = ((unsigned int)u) << 16;
    return __builtin_bit_cast(float, v);
}
__device__ __forceinline__ unsigned short f2bf(float f) {
    unsigned int u = __builtin_bit_cast(unsigned int, f);
    unsigned int lsb = (u >> 16) & 1u;
    u += 0x7fffu + lsb;   // round-to-nearest-even (finite inputs)
    return (unsigned short)(u >> 16);
}

// global->LDS DMA, 16 B per lane; dest = ldsbase + lane*16 (wave-uniform base)
__device__ __forceinline__ void load_lds16(const void* g, void* l) {
    __builtin_amdgcn_global_load_lds(
        (const __attribute__((address_space(1))) unsigned int*)g,
        (__attribute__((address_space(3))) unsigned int*)l,
        16, 0, 0);
}

// ---------------------------------------------------------------------------
// Kernel 0: w_comb2[o][c] = (sum_k w_W[o,k] * w_pc[k,c]) * w_dw[c], stored
// PRE-SWIZZLED in MFMA fragment order:
//   frag[ob][ks][lane][e] = w_comb2[ob*16 + (lane&15)][ks*32 + (lane>>4)*8 + e]
// ---------------------------------------------------------------------------
__global__ __launch_bounds__(256)
void build_wcomb(const float* __restrict__ w_dw,
                 const float* __restrict__ w_pc,
                 const float* __restrict__ w_W,
                 unsigned short* __restrict__ wfrag) {
    const int o = blockIdx.x;
    const int c = threadIdx.x;
    float acc = 0.f;
#pragma unroll 8
    for (int k = 0; k < Cn; ++k)
        acc = fmaf(w_W[o * Cn + k], w_pc[k * Cn + c], acc);
    const int ob = o >> 4, lr = o & 15;
    const int ks = c >> 5, lg = (c & 31) >> 3, e = c & 7;
    const int lane = (lg << 4) + lr;
    wfrag[((((ob << 3) + ks) << 6) + lane) * 8 + e] = f2bf(acc * w_dw[c]);
}

// ---------------------------------------------------------------------------
// Kernel 1: per 64-pixel tile: transpose x -> x_t[B,H,W,C] (bf16) and compute
// sample coords (ix, iy) from tanh(w_off . x + b_off).
// ---------------------------------------------------------------------------
__global__ __launch_bounds__(256)
void prep_kernel(const float* __restrict__ x,
                 const float* __restrict__ w_off,
                 const float* __restrict__ b_off,
                 unsigned short* __restrict__ x_t,    // [B*HW][C] bf16
                 float2* __restrict__ coords) {       // [B*HW] (ix, iy)
    __shared__ __align__(16) char tile[64 * 512];     // 64 pix x 256 bf16, XOR-swizzled
    __shared__ float partial[4][64][2];
    const int t = threadIdx.x;
    const int lane = t & 63;
    const int wv = t >> 6;                 // 0..3 (wave id)
    int blk = blockIdx.x;                  // 2048 blocks
    blk = ((blk & 7) << 8) | (blk >> 3);   // XCD swizzle: image b = XCD id
    const int b = blk >> 8;
    const int p0 = (blk & 255) << 6;
    const float* xp = x + ((size_t)b * Cn) * HWn + p0;

    float s0 = 0.f, s1 = 0.f;
#pragma unroll 8
    for (int i = 0; i < 64; ++i) {
        int c = (wv << 6) + i;
        float v = xp[(size_t)c * HWn + lane];
        s0 = fmaf(v, w_off[c], s0);
        s1 = fmaf(v, w_off[Cn + c], s1);
        int byte = (lane << 9) + (((c << 1)) ^ ((lane & 7) << 4));
        *reinterpret_cast<unsigned short*>(tile + byte) = f2bf(v);
    }
    partial[wv][lane][0] = s0;
    partial[wv][lane][1] = s1;
    __syncthreads();

    if (t < 64) {
        float o0 = partial[0][t][0] + partial[1][t][0] + partial[2][t][0] + partial[3][t][0] + b_off[0];
        float o1 = partial[0][t][1] + partial[1][t][1] + partial[2][t][1] + partial[3][t][1] + b_off[1];
        o0 = tanhf(o0);
        o1 = tanhf(o1);
        int p = p0 + t;
        int yy = p >> 7, xx = p & 127;
        float gx = fminf(fmaxf(-1.f + xx * (2.f / 127.f) + o0, -1.f), 1.f);
        float gy = fminf(fmaxf(-1.f + yy * (2.f / 127.f) + o1, -1.f), 1.f);
        // ix = ((gx+1)*W - 1)/2 = 64*gx + 63.5 ; same for iy (H=W=128)
        coords[(size_t)b * HWn + p] = make_float2(gx * 64.f + 63.5f, gy * 64.f + 63.5f);
    }

    // write-out: 4 threads per pixel, 64 channels each (contiguous bf16 rows)
    const int pp = t >> 2, cc = t & 3;
    unsigned short* dst = x_t + ((size_t)(b * HWn + p0 + pp)) * Cn + (cc << 6);
#pragma unroll
    for (int j = 0; j < 8; ++j) {
        int c2 = ((cc << 6) + (j << 3)) << 1;
        int byte = (pp << 9) + (c2 ^ ((pp & 7) << 4));
        *reinterpret_cast<u32x4*>(dst + (j << 3)) = *reinterpret_cast<const u32x4*>(tile + byte);
    }
}

// ---------------------------------------------------------------------------
// Kernel 2: per 32-pixel tile, 512 threads (8 waves). DMA-gather 4 corner LDS
// buffers (linear dest, source-swizzled chunks), sync, SINGLE blend pass
// (each (px,chunk) blended by exactly one thread, written in place into
// As[0] = samp), sync, MFMA (8 waves x 32-o slices) + fused epilogue.
//   out[o][p] = sum_c w_comb2[o][c]*samp[p][c] + b_W[o] + x[b][o][p]
// ---------------------------------------------------------------------------
__global__ __launch_bounds__(512, 2)
void main_kernel(const float* __restrict__ x,
                 const float* __restrict__ b_W,
                 const unsigned short* __restrict__ x_t,
                 const float2* __restrict__ coords,
                 const unsigned short* __restrict__ wfrag,
                 float* __restrict__ out) {
    __shared__ __align__(16) char As[4][32 * 512];   // 4 corners x 32px x 512B
    __shared__ __align__(16) float4 wts[32];         // per-pixel corner weights
    const int t = threadIdx.x;
    const int lane = t & 63;
    const int wid = t >> 6;          // 0..7
    int blk = blockIdx.x;            // 4096 blocks
    blk = ((blk & 7) << 9) | (blk >> 3);   // XCD swizzle: image b = XCD id
    const int b = blk >> 9;
    const int p0 = (blk & 511) << 5;       // 32-px tile
    const size_t pixbase = (size_t)b * HWn + p0;
    const unsigned short* xtb = x_t + (size_t)b * HWn * Cn;

    // ---- weights setup: one thread per pixel ----
    if (t < 32) {
        float2 co = coords[pixbase + t];
        float ix = co.x, iy = co.y;
        float fx = floorf(ix), fy = floorf(iy);
        int ix0 = (int)fx, iy0 = (int)fy;
        float wx1 = ix - fx, wy1 = iy - fy;
        float wx0 = 1.f - wx1, wy0 = 1.f - wy1;
        bool vx0 = (ix0 >= 0) && (ix0 < Wn);
        bool vx1 = (ix0 >= -1) && (ix0 < Wn - 1);
        bool vy0 = (iy0 >= 0) && (iy0 < Hn);
        bool vy1 = (iy0 >= -1) && (iy0 < Hn - 1);
        float4 w;
        w.x = (vy0 && vx0) ? wy0 * wx0 : 0.f;
        w.y = (vy0 && vx1) ? wy0 * wx1 : 0.f;
        w.z = (vy1 && vx0) ? wy1 * wx0 : 0.f;
        w.w = (vy1 && vx1) ? wy1 * wx1 : 0.f;
        wts[t] = w;
    }

    // ---- DMA gather: wave wid owns px [wid*4, wid*4+4) as 2 pixel-pairs ----
    {
        const int hp = lane >> 5;           // which pixel of the pair
        const int j = lane & 31;            // LDS chunk index (16B units)
        float2 co[2];
#pragma unroll
        for (int i = 0; i < 2; ++i)
            co[i] = coords[pixbase + (wid << 2) + (i << 1) + hp];

#pragma unroll
        for (int i = 0; i < 2; ++i) {
            const int p = (wid << 2) + (i << 1);   // pair base (wave-uniform)
            const int px = p + hp;                 // this lane's pixel
            float ix = co[i].x, iy = co[i].y;
            int ix0 = (int)floorf(ix), iy0 = (int)floorf(iy);
            int cx0 = min(max(ix0, 0), Wn - 1), cx1 = min(max(ix0 + 1, 0), Wn - 1);
            int cy0 = min(max(iy0, 0), Hn - 1), cy1 = min(max(iy0 + 1, 0), Hn - 1);
            const int gch = (j ^ (px & 15)) << 3;  // swizzled global channel base
            const unsigned short* s00 = xtb + (size_t)(cy0 * Wn + cx0) * Cn + gch;
            const unsigned short* s01 = xtb + (size_t)(cy0 * Wn + cx1) * Cn + gch;
            const unsigned short* s10 = xtb + (size_t)(cy1 * Wn + cx0) * Cn + gch;
            const unsigned short* s11 = xtb + (size_t)(cy1 * Wn + cx1) * Cn + gch;
            load_lds16(s00, &As[0][p << 9]);
            load_lds16(s01, &As[1][p << 9]);
            load_lds16(s10, &As[2][p << 9]);
            load_lds16(s11, &As[3][p << 9]);
        }
    }
    __syncthreads();   // drains DMA (vmcnt) + orders wts

    // ---- blend pass: each (px, chunk) by exactly one thread, in place ----
    {
        const int px = t >> 4;             // 0..31
        const float4 w = wts[px];
#pragma unroll
        for (int q = 0; q < 2; ++q) {
            const int kc = (t & 15) + (q << 4);          // 0..31
            const int off = (px << 9) + ((kc ^ (px & 15)) << 4);
            u16x8 c00 = *reinterpret_cast<const u16x8*>(&As[0][off]);
            u16x8 c01 = *reinterpret_cast<const u16x8*>(&As[1][off]);
            u16x8 c10 = *reinterpret_cast<const u16x8*>(&As[2][off]);
            u16x8 c11 = *reinterpret_cast<const u16x8*>(&As[3][off]);
            u16x8 res;
#pragma unroll
            for (int e = 0; e < 8; ++e) {
                float r = w.x * bf2f(c00[e]) + w.y * bf2f(c01[e])
                        + w.z * bf2f(c10[e]) + w.w * bf2f(c11[e]);
                res[e] = f2bf(r);
            }
            *reinterpret_cast<u16x8*>(&As[0][off]) = res;  // samp in place
        }
    }
    __syncthreads();

    // ---- MFMA phase: 8 waves; wave wid owns o-range [wid*32, +32), all 32 px
    const int lr = lane & 15;
    const int lg = lane >> 4;
    f32x4 acc[2][2];
#pragma unroll
    for (int m = 0; m < 2; ++m)
#pragma unroll
        for (int n = 0; n < 2; ++n)
            acc[m][n] = (f32x4){0.f, 0.f, 0.f, 0.f};

#pragma unroll
    for (int ks = 0; ks < 8; ++ks) {
        bfrag8 a[2], bb[2];
        const int kc = (ks << 2) + lg;           // 16B chunk index 0..31
#pragma unroll
        for (int n = 0; n < 2; ++n) {
            const int pr = (n << 4) + lr;
            const int off = (pr << 9) + ((kc ^ (pr & 15)) << 4);
            bb[n] = *reinterpret_cast<const bfrag8*>(&As[0][off]);
        }
#pragma unroll
        for (int m = 0; m < 2; ++m) {
            // coalesced fragment load: 64 lanes x 16 B contiguous (1 KB)
            const int ob = (wid << 1) + m;
            const unsigned short* src = wfrag + ((((ob << 3) + ks) << 6) + lane) * 8;
            a[m] = *reinterpret_cast<const bfrag8*>(src);
        }
#pragma unroll
        for (int m = 0; m < 2; ++m)
#pragma unroll
            for (int n = 0; n < 2; ++n)
                acc[m][n] = __builtin_amdgcn_mfma_f32_16x16x32_bf16(a[m], bb[n], acc[m][n], 0, 0, 0);
    }

    // ---- epilogue: D col = lane&15 (pixel), row = lg*4+reg (o); nt out-store
#pragma unroll
    for (int m = 0; m < 2; ++m) {
#pragma unroll
        for (int r = 0; r < 4; ++r) {
            int o = (wid << 5) + (m << 4) + (lg << 2) + r;
            float bw = b_W[o];
            size_t rowbase = ((size_t)b * Cn + o) * HWn + p0;
#pragma unroll
            for (int n = 0; n < 2; ++n) {
                size_t idx = rowbase + (n << 4) + lr;
                __builtin_nontemporal_store(acc[m][n][r] + bw + x[idx], &out[idx]);
            }
        }
    }
}

extern "C" void kernel_launch(void* const* d_in, const int* in_sizes, int n_in,
                              void* d_out, int out_size, void* d_ws, size_t ws_size,
                              hipStream_t stream) {
    const float* x     = (const float*)d_in[0];
    const float* w_dw  = (const float*)d_in[1];
    const float* w_off = (const float*)d_in[2];
    const float* b_off = (const float*)d_in[3];
    const float* w_pc  = (const float*)d_in[4];
    const float* w_W   = (const float*)d_in[5];
    const float* b_W   = (const float*)d_in[6];
    float* out = (float*)d_out;

    char* ws = (char*)d_ws;
    unsigned short* x_t   = (unsigned short*)ws;                        // 67,108,864 B
    float2* coords        = (float2*)(ws + 67108864);                   //  1,048,576 B
    unsigned short* wcomb = (unsigned short*)(ws + 67108864 + 1048576); //    131,072 B

    build_wcomb<<<dim3(256), dim3(256), 0, stream>>>(w_dw, w_pc, w_W, wcomb);
    prep_kernel<<<dim3(2048), dim3(256), 0, stream>>>(x, w_off, b_off, x_t, coords);
    main_kernel<<<dim3(4096), dim3(512), 0, stream>>>(x, b_W, x_t, coords, wcomb, out);
}

// Round 14
// 117.286 us; speedup vs baseline: 1.2474x; 1.0143x over previous
//
#include <hip/hip_runtime.h>
#include <hip/hip_bf16.h>

#define Bn 8
#define Cn 256
#define Hn 128
#define Wn 128
#define HWn (Hn * Wn)

typedef __attribute__((ext_vector_type(8))) short bfrag8;       // MFMA A/B frag (8 bf16)
typedef __attribute__((ext_vector_type(8))) unsigned short u16x8;
typedef __attribute__((ext_vector_type(4))) float f32x4;
typedef __attribute__((ext_vector_type(4))) unsigned int u32x4;

__device__ __forceinline__ float bf2f(unsigned short u) {
    unsigned int v = ((unsigned int)u) << 16;
    return __builtin_bit_cast(float, v);
}
__device__ __forceinline__ unsigned short f2bf(float f) {
    unsigned int u = __builtin_bit_cast(unsigned int, f);
    unsigned int lsb = (u >> 16) & 1u;
    u += 0x7fffu + lsb;   // round-to-nearest-even (finite inputs)
    return (unsigned short)(u >> 16);
}

// global->LDS DMA, 16 B per lane; dest = ldsbase + lane*16 (wave-uniform base)
__device__ __forceinline__ void load_lds16(const void* g, void* l) {
    __builtin_amdgcn_global_load_lds(
        (const __attribute__((address_space(1))) unsigned int*)g,
        (__attribute__((address_space(3))) unsigned int*)l,
        16, 0, 0);
}

// ---------------------------------------------------------------------------
// Kernel 0: w_comb2[o][c] = (sum_k w_W[o,k] * w_pc[k,c]) * w_dw[c], stored
// PRE-SWIZZLED in MFMA fragment order:
//   frag[ob][ks][lane][e] = w_comb2[ob*16 + (lane&15)][ks*32 + (lane>>4)*8 + e]
// ---------------------------------------------------------------------------
__global__ __launch_bounds__(256)
void build_wcomb(const float* __restrict__ w_dw,
                 const float* __restrict__ w_pc,
                 const float* __restrict__ w_W,
                 unsigned short* __restrict__ wfrag) {
    const int o = blockIdx.x;
    const int c = threadIdx.x;
    float acc = 0.f;
#pragma unroll 8
    for (int k = 0; k < Cn; ++k)
        acc = fmaf(w_W[o * Cn + k], w_pc[k * Cn + c], acc);
    const int ob = o >> 4, lr = o & 15;
    const int ks = c >> 5, lg = (c & 31) >> 3, e = c & 7;
    const int lane = (lg << 4) + lr;
    wfrag[((((ob << 3) + ks) << 6) + lane) * 8 + e] = f2bf(acc * w_dw[c]);
}

// ---------------------------------------------------------------------------
// Kernel 1: per 64-pixel tile: transpose x -> x_t[B,H,W,C] (bf16) and compute
// sample coords (ix, iy) from tanh(w_off . x + b_off).
// VECTORIZED: each lane loads float4 (4 px of one channel) -> 16 x 1KB load
// instructions per wave, all independent. Offset sums reduced via shfl_xor.
// ---------------------------------------------------------------------------
__global__ __launch_bounds__(256, 4)
void prep_kernel(const float* __restrict__ x,
                 const float* __restrict__ w_off,
                 const float* __restrict__ b_off,
                 unsigned short* __restrict__ x_t,    // [B*HW][C] bf16
                 float2* __restrict__ coords) {       // [B*HW] (ix, iy)
    __shared__ __align__(16) char tile[64 * 512];     // 64 pix x 256 bf16, XOR-swizzled
    __shared__ float part0[4][64], part1[4][64];      // per-wave pixel sums
    const int t = threadIdx.x;
    const int lane = t & 63;
    const int wv = t >> 6;                 // 0..3 (wave id)
    int blk = blockIdx.x;                  // 2048 blocks
    blk = ((blk & 7) << 8) | (blk >> 3);   // XCD swizzle: image b = XCD id
    const int b = blk >> 8;
    const int p0 = (blk & 255) << 6;
    const float* xp = x + ((size_t)b * Cn) * HWn + p0;

    const int lg = lane >> 4;              // channel sub-index 0..3
    const int px4 = lane & 15;             // pixel-quad index 0..15
    f32x4 s0 = {0.f, 0.f, 0.f, 0.f}, s1 = {0.f, 0.f, 0.f, 0.f};

#pragma unroll
    for (int i = 0; i < 16; ++i) {
        const int c = (wv << 6) + (i << 2) + lg;
        f32x4 v = *reinterpret_cast<const f32x4*>(xp + (size_t)c * HWn + (px4 << 2));
        const float wa = w_off[c];
        const float wb = w_off[Cn + c];
#pragma unroll
        for (int k = 0; k < 4; ++k) {
            s0[k] = fmaf(v[k], wa, s0[k]);
            s1[k] = fmaf(v[k], wb, s1[k]);
            const int px = (px4 << 2) + k;
            const int byte = (px << 9) + (((c << 1)) ^ ((px & 7) << 4));
            *reinterpret_cast<unsigned short*>(tile + byte) = f2bf(v[k]);
        }
    }

    // reduce across the 4 channel sub-groups (lanes ±16, ±32)
#pragma unroll
    for (int k = 0; k < 4; ++k) {
        s0[k] += __shfl_xor(s0[k], 16);
        s0[k] += __shfl_xor(s0[k], 32);
        s1[k] += __shfl_xor(s1[k], 16);
        s1[k] += __shfl_xor(s1[k], 32);
    }
    if (lg == 0) {
#pragma unroll
        for (int k = 0; k < 4; ++k) {
            part0[wv][(px4 << 2) + k] = s0[k];
            part1[wv][(px4 << 2) + k] = s1[k];
        }
    }
    __syncthreads();

    if (t < 64) {
        float o0 = part0[0][t] + part0[1][t] + part0[2][t] + part0[3][t] + b_off[0];
        float o1 = part1[0][t] + part1[1][t] + part1[2][t] + part1[3][t] + b_off[1];
        o0 = tanhf(o0);
        o1 = tanhf(o1);
        int p = p0 + t;
        int yy = p >> 7, xx = p & 127;
        float gx = fminf(fmaxf(-1.f + xx * (2.f / 127.f) + o0, -1.f), 1.f);
        float gy = fminf(fmaxf(-1.f + yy * (2.f / 127.f) + o1, -1.f), 1.f);
        // ix = ((gx+1)*W - 1)/2 = 64*gx + 63.5 ; same for iy (H=W=128)
        coords[(size_t)b * HWn + p] = make_float2(gx * 64.f + 63.5f, gy * 64.f + 63.5f);
    }

    // write-out: 4 threads per pixel, 64 channels each (contiguous bf16 rows)
    const int pp = t >> 2, cc = t & 3;
    unsigned short* dst = x_t + ((size_t)(b * HWn + p0 + pp)) * Cn + (cc << 6);
#pragma unroll
    for (int j = 0; j < 8; ++j) {
        int c2 = ((cc << 6) + (j << 3)) << 1;
        int byte = (pp << 9) + (c2 ^ ((pp & 7) << 4));
        *reinterpret_cast<u32x4*>(dst + (j << 3)) = *reinterpret_cast<const u32x4*>(tile + byte);
    }
}

// ---------------------------------------------------------------------------
// Kernel 2: per 32-pixel tile, 512 threads (8 waves). DMA-gather 4 corner LDS
// buffers (linear dest, source-swizzled chunks), sync, SINGLE blend pass
// (each (px,chunk) blended by exactly one thread, written in place into
// As[0] = samp), sync, MFMA (8 waves x 32-o slices) + fused epilogue.
//   out[o][p] = sum_c w_comb2[o][c]*samp[p][c] + b_W[o] + x[b][o][p]
// ---------------------------------------------------------------------------
__global__ __launch_bounds__(512, 2)
void main_kernel(const float* __restrict__ x,
                 const float* __restrict__ b_W,
                 const unsigned short* __restrict__ x_t,
                 const float2* __restrict__ coords,
                 const unsigned short* __restrict__ wfrag,
                 float* __restrict__ out) {
    __shared__ __align__(16) char As[4][32 * 512];   // 4 corners x 32px x 512B
    __shared__ __align__(16) float4 wts[32];         // per-pixel corner weights
    const int t = threadIdx.x;
    const int lane = t & 63;
    const int wid = t >> 6;          // 0..7
    int blk = blockIdx.x;            // 4096 blocks
    blk = ((blk & 7) << 9) | (blk >> 3);   // XCD swizzle: image b = XCD id
    const int b = blk >> 9;
    const int p0 = (blk & 511) << 5;       // 32-px tile
    const size_t pixbase = (size_t)b * HWn + p0;
    const unsigned short* xtb = x_t + (size_t)b * HWn * Cn;

    // ---- weights setup: one thread per pixel ----
    if (t < 32) {
        float2 co = coords[pixbase + t];
        float ix = co.x, iy = co.y;
        float fx = floorf(ix), fy = floorf(iy);
        int ix0 = (int)fx, iy0 = (int)fy;
        float wx1 = ix - fx, wy1 = iy - fy;
        float wx0 = 1.f - wx1, wy0 = 1.f - wy1;
        bool vx0 = (ix0 >= 0) && (ix0 < Wn);
        bool vx1 = (ix0 >= -1) && (ix0 < Wn - 1);
        bool vy0 = (iy0 >= 0) && (iy0 < Hn);
        bool vy1 = (iy0 >= -1) && (iy0 < Hn - 1);
        float4 w;
        w.x = (vy0 && vx0) ? wy0 * wx0 : 0.f;
        w.y = (vy0 && vx1) ? wy0 * wx1 : 0.f;
        w.z = (vy1 && vx0) ? wy1 * wx0 : 0.f;
        w.w = (vy1 && vx1) ? wy1 * wx1 : 0.f;
        wts[t] = w;
    }

    // ---- DMA gather: wave wid owns px [wid*4, wid*4+4) as 2 pixel-pairs ----
    {
        const int hp = lane >> 5;           // which pixel of the pair
        const int j = lane & 31;            // LDS chunk index (16B units)
        float2 co[2];
#pragma unroll
        for (int i = 0; i < 2; ++i)
            co[i] = coords[pixbase + (wid << 2) + (i << 1) + hp];

#pragma unroll
        for (int i = 0; i < 2; ++i) {
            const int p = (wid << 2) + (i << 1);   // pair base (wave-uniform)
            const int px = p + hp;                 // this lane's pixel
            float ix = co[i].x, iy = co[i].y;
            int ix0 = (int)floorf(ix), iy0 = (int)floorf(iy);
            int cx0 = min(max(ix0, 0), Wn - 1), cx1 = min(max(ix0 + 1, 0), Wn - 1);
            int cy0 = min(max(iy0, 0), Hn - 1), cy1 = min(max(iy0 + 1, 0), Hn - 1);
            const int gch = (j ^ (px & 15)) << 3;  // swizzled global channel base
            const unsigned short* s00 = xtb + (size_t)(cy0 * Wn + cx0) * Cn + gch;
            const unsigned short* s01 = xtb + (size_t)(cy0 * Wn + cx1) * Cn + gch;
            const unsigned short* s10 = xtb + (size_t)(cy1 * Wn + cx0) * Cn + gch;
            const unsigned short* s11 = xtb + (size_t)(cy1 * Wn + cx1) * Cn + gch;
            load_lds16(s00, &As[0][p << 9]);
            load_lds16(s01, &As[1][p << 9]);
            load_lds16(s10, &As[2][p << 9]);
            load_lds16(s11, &As[3][p << 9]);
        }
    }
    __syncthreads();   // drains DMA (vmcnt) + orders wts

    // ---- blend pass: each (px, chunk) by exactly one thread, in place ----
    {
        const int px = t >> 4;             // 0..31
        const float4 w = wts[px];
#pragma unroll
        for (int q = 0; q < 2; ++q) {
            const int kc = (t & 15) + (q << 4);          // 0..31
            const int off = (px << 9) + ((kc ^ (px & 15)) << 4);
            u16x8 c00 = *reinterpret_cast<const u16x8*>(&As[0][off]);
            u16x8 c01 = *reinterpret_cast<const u16x8*>(&As[1][off]);
            u16x8 c10 = *reinterpret_cast<const u16x8*>(&As[2][off]);
            u16x8 c11 = *reinterpret_cast<const u16x8*>(&As[3][off]);
            u16x8 res;
#pragma unroll
            for (int e = 0; e < 8; ++e) {
                float r = w.x * bf2f(c00[e]) + w.y * bf2f(c01[e])
                        + w.z * bf2f(c10[e]) + w.w * bf2f(c11[e]);
                res[e] = f2bf(r);
            }
            *reinterpret_cast<u16x8*>(&As[0][off]) = res;  // samp in place
        }
    }
    __syncthreads();

    // ---- MFMA phase: 8 waves; wave wid owns o-range [wid*32, +32), all 32 px
    const int lr = lane & 15;
    const int lg = lane >> 4;
    f32x4 acc[2][2];
#pragma unroll
    for (int m = 0; m < 2; ++m)
#pragma unroll
        for (int n = 0; n < 2; ++n)
            acc[m][n] = (f32x4){0.f, 0.f, 0.f, 0.f};

#pragma unroll
    for (int ks = 0; ks < 8; ++ks) {
        bfrag8 a[2], bb[2];
        const int kc = (ks << 2) + lg;           // 16B chunk index 0..31
#pragma unroll
        for (int n = 0; n < 2; ++n) {
            const int pr = (n << 4) + lr;
            const int off = (pr << 9) + ((kc ^ (pr & 15)) << 4);
            bb[n] = *reinterpret_cast<const bfrag8*>(&As[0][off]);
        }
#pragma unroll
        for (int m = 0; m < 2; ++m) {
            // coalesced fragment load: 64 lanes x 16 B contiguous (1 KB)
            const int ob = (wid << 1) + m;
            const unsigned short* src = wfrag + ((((ob << 3) + ks) << 6) + lane) * 8;
            a[m] = *reinterpret_cast<const bfrag8*>(src);
        }
#pragma unroll
        for (int m = 0; m < 2; ++m)
#pragma unroll
            for (int n = 0; n < 2; ++n)
                acc[m][n] = __builtin_amdgcn_mfma_f32_16x16x32_bf16(a[m], bb[n], acc[m][n], 0, 0, 0);
    }

    // ---- epilogue: D col = lane&15 (pixel), row = lg*4+reg (o); nt out-store
#pragma unroll
    for (int m = 0; m < 2; ++m) {
#pragma unroll
        for (int r = 0; r < 4; ++r) {
            int o = (wid << 5) + (m << 4) + (lg << 2) + r;
            float bw = b_W[o];
            size_t rowbase = ((size_t)b * Cn + o) * HWn + p0;
#pragma unroll
            for (int n = 0; n < 2; ++n) {
                size_t idx = rowbase + (n << 4) + lr;
                __builtin_nontemporal_store(acc[m][n][r] + bw + x[idx], &out[idx]);
            }
        }
    }
}

extern "C" void kernel_launch(void* const* d_in, const int* in_sizes, int n_in,
                              void* d_out, int out_size, void* d_ws, size_t ws_size,
                              hipStream_t stream) {
    const float* x     = (const float*)d_in[0];
    const float* w_dw  = (const float*)d_in[1];
    const float* w_off = (const float*)d_in[2];
    const float* b_off = (const float*)d_in[3];
    const float* w_pc  = (const float*)d_in[4];
    const float* w_W   = (const float*)d_in[5];
    const float* b_W   = (const float*)d_in[6];
    float* out = (float*)d_out;

    char* ws = (char*)d_ws;
    unsigned short* x_t   = (unsigned short*)ws;                        // 67,108,864 B
    float2* coords        = (float2*)(ws + 67108864);                   //  1,048,576 B
    unsigned short* wcomb = (unsigned short*)(ws + 67108864 + 1048576); //    131,072 B

    build_wcomb<<<dim3(256), dim3(256), 0, stream>>>(w_dw, w_pc, w_W, wcomb);
    prep_kernel<<<dim3(2048), dim3(256), 0, stream>>>(x, w_off, b_off, x_t, coords);
    main_kernel<<<dim3(4096), dim3(512), 0, stream>>>(x, b_W, x_t, coords, wcomb, out);
}